// Round 6
// baseline (231.054 us; speedup 1.0000x reference)
//
#include <hip/hip_runtime.h>

typedef unsigned short u16;
typedef unsigned int   u32;
typedef __attribute__((ext_vector_type(8))) short short8;
typedef __attribute__((ext_vector_type(4))) float f32x4;

#define AS1 __attribute__((address_space(1)))
#define AS3 __attribute__((address_space(3)))

#define NSEQ  1025
#define BB    8
#define DD    768
#define HH    12
#define MROWS 8200   // B*N valid rows
#define MPAD  8320   // padded to 65*128
#define KPAD  1088   // keys padded to 17*64

__device__ __forceinline__ void gl2lds16(const void* g, void* l) {
  __builtin_amdgcn_global_load_lds((const AS1 u32*)g, (AS3 u32*)l, 16, 0, 0);
}
__device__ __forceinline__ u16 f2bf(float f) {
  u32 u = __float_as_uint(f);
  return (u16)((u + 0x7FFFu + ((u >> 16) & 1u)) >> 16);
}
__device__ __forceinline__ float bf2f(u16 u) { return __uint_as_float(((u32)u) << 16); }

// ---------------------------------------------------------------------------
// prep: cast x -> xb bf16 [MPAD x 768] (transposed (n,b)->(b,n), pad rows = 0),
//       w_qkv rows [768,2304) -> wkv bf16 [1536 x 768],
//       w_proj -> wpj bf16 [768 x 768]
// ---------------------------------------------------------------------------
__global__ __launch_bounds__(256) void prep(const float* __restrict__ x,
                                            const float* __restrict__ wqkv,
                                            const float* __restrict__ wproj,
                                            u16* __restrict__ xb,
                                            u16* __restrict__ wkv,
                                            u16* __restrict__ wpj) {
  const int XB_G  = MPAD * 192;   // float4 groups
  const int WKV_G = 1536 * 192;
  const int WPJ_G = 768 * 192;
  int g = blockIdx.x * 256 + threadIdx.x;
  float4 v;
  u16* dst;
  size_t di;
  if (g < XB_G) {
    int m = g / 192, e4 = g - m * 192;
    if (m < MROWS) {
      int bb = m / NSEQ, ns = m - bb * NSEQ;
      v = ((const float4*)x)[(size_t)(ns * BB + bb) * 192 + e4];
    } else {
      v.x = v.y = v.z = v.w = 0.f;
    }
    dst = xb; di = (size_t)g;
  } else if (g < XB_G + WKV_G) {
    int r = g - XB_G;
    v = ((const float4*)wqkv)[(size_t)147456 + r];  // skip first 768 rows
    dst = wkv; di = (size_t)r;
  } else if (g < XB_G + WKV_G + WPJ_G) {
    int r = g - XB_G - WKV_G;
    v = ((const float4*)wproj)[r];
    dst = wpj; di = (size_t)r;
  } else {
    return;
  }
  uint2 o;
  o.x = (u32)f2bf(v.x) | ((u32)f2bf(v.y) << 16);
  o.y = (u32)f2bf(v.z) | ((u32)f2bf(v.w) << 16);
  ((uint2*)dst)[di] = o;
}

// ---------------------------------------------------------------------------
// gemm_bt: C[m,n] = sum_k A[m,k]*W[n,k]; 128x128 tile, BK=64. XCD-aware 1D
// grid. NT = n-tiles. MODE 0: bf16 store. MODE 1: +bias, fp32 scatter.
// ---------------------------------------------------------------------------
template <int MODE, int NT>
__global__ __launch_bounds__(256) void gemm_bt(const u16* __restrict__ A,
                                               const u16* __restrict__ W,
                                               u16* __restrict__ Cbf,
                                               float* __restrict__ Cf,
                                               const float* __restrict__ bias,
                                               int ldc) {
  __shared__ u16 sA[128 * 64];
  __shared__ u16 sW[128 * 64];
  const int id = blockIdx.x;
  const int rx = id & 7, qx = id >> 3;
  const int kq = qx / NT;
  const int m_t = rx + (kq << 3);
  if (m_t > 64) return;
  const int n_t = qx - kq * NT;
  const int m0 = m_t << 7, n0 = n_t << 7;

  const int tid = threadIdx.x;
  const int w = tid >> 6, lane = tid & 63;
  const int wm = w & 1, wn = w >> 1;
  const int lc = lane & 15, lr = lane >> 4;

  f32x4 zero4 = {0.f, 0.f, 0.f, 0.f};
  f32x4 acc[4][4];
#pragma unroll
  for (int i = 0; i < 4; ++i)
#pragma unroll
    for (int j = 0; j < 4; ++j) acc[i][j] = zero4;

  const int r0 = tid >> 3;        // staging row 0..31 (+32 per chunk j)
  const int ko = (tid & 7) << 3;  // k-offset in elements
  const u16* gA = A + (size_t)(m0 + r0) * DD + ko;
  const u16* gW = W + (size_t)(n0 + r0) * DD + ko;
  char* lA = (char*)sA + tid * 16;
  char* lW = (char*)sW + tid * 16;

#pragma unroll 1
  for (int kt = 0; kt < 12; ++kt) {
    __syncthreads();
#pragma unroll
    for (int j = 0; j < 4; ++j) {
      gl2lds16(gA + (size_t)j * 32 * DD + kt * 64, lA + j * 4096);
      gl2lds16(gW + (size_t)j * 32 * DD + kt * 64, lW + j * 4096);
    }
    __syncthreads();
#pragma unroll
    for (int kk = 0; kk < 2; ++kk) {
      short8 af[4], wf[4];
#pragma unroll
      for (int mt = 0; mt < 4; ++mt)
        af[mt] = *(const short8*)((char*)sA + ((wm << 6) + (mt << 4) + lc) * 128 + (kk << 6) + (lr << 4));
#pragma unroll
      for (int nt = 0; nt < 4; ++nt)
        wf[nt] = *(const short8*)((char*)sW + ((wn << 6) + (nt << 4) + lc) * 128 + (kk << 6) + (lr << 4));
#pragma unroll
      for (int mt = 0; mt < 4; ++mt)
#pragma unroll
        for (int nt = 0; nt < 4; ++nt)
          acc[mt][nt] = __builtin_amdgcn_mfma_f32_16x16x32_bf16(af[mt], wf[nt], acc[mt][nt], 0, 0, 0);
    }
  }

  if (MODE == 0) {
#pragma unroll
    for (int mt = 0; mt < 4; ++mt)
#pragma unroll
      for (int r = 0; r < 4; ++r) {
        int m = m0 + (wm << 6) + (mt << 4) + (lr << 2) + r;
        if (m < MROWS) {
          size_t base = (size_t)m * ldc + n0 + (wn << 6) + lc;
#pragma unroll
          for (int nt = 0; nt < 4; ++nt) Cbf[base + (nt << 4)] = f2bf(acc[mt][nt][r]);
        }
      }
  } else {
    float b4[4];
#pragma unroll
    for (int nt = 0; nt < 4; ++nt) b4[nt] = bias[n0 + (wn << 6) + (nt << 4) + lc];
#pragma unroll
    for (int mt = 0; mt < 4; ++mt)
#pragma unroll
      for (int r = 0; r < 4; ++r) {
        int m = m0 + (wm << 6) + (mt << 4) + (lr << 2) + r;
        if (m < MROWS) {
          int bb = m / NSEQ;
          int ns = m - bb * NSEQ;
          float* o = Cf + (size_t)ns * (BB * DD) + bb * DD + n0 + (wn << 6) + lc;
#pragma unroll
          for (int nt = 0; nt < 4; ++nt) o[nt << 4] = acc[mt][nt][r] + b4[nt];
        }
      }
  }
}

// ---------------------------------------------------------------------------
// transpose_v: vT[bh][d][key] raw (KPAD cols, zero-padded) AND
//              vn[bh][key][64] = v/max(||v||,eps) bf16 (zero pad rows)
// ---------------------------------------------------------------------------
__global__ __launch_bounds__(256) void transpose_v(const u16* __restrict__ kv,
                                                   u16* __restrict__ vT,
                                                   u16* __restrict__ vn) {
  __shared__ u16 tile[64][72];
  __shared__ float red[256];
  __shared__ float sInv[64];
  int bid = blockIdx.x;
  int kc = bid % 17;
  int t2 = bid / 17;
  int h = t2 % HH, b = t2 / HH;
  int tid = threadIdx.x;
  int kl = tid >> 2, dc = (tid & 3) << 4;
  int key = kc * 64 + kl;
  u32 vals[8];
  if (key < NSEQ) {
    const u32* g = (const u32*)(kv + ((size_t)b * NSEQ + key) * 1536 + DD + h * 64 + dc);
#pragma unroll
    for (int i = 0; i < 8; ++i) vals[i] = g[i];
  } else {
#pragma unroll
    for (int i = 0; i < 8; ++i) vals[i] = 0;
  }
  float part = 0.f;
#pragma unroll
  for (int i = 0; i < 8; ++i) {
    float a = bf2f((u16)(vals[i] & 0xFFFF));
    float c = bf2f((u16)(vals[i] >> 16));
    part += a * a + c * c;
    ((u32*)&tile[kl][dc])[i] = vals[i];
  }
  red[tid] = part;
  __syncthreads();
  if ((tid & 3) == 0) {
    float s = red[tid] + red[tid + 1] + red[tid + 2] + red[tid + 3];
    sInv[kl] = (key < NSEQ) ? 1.0f / fmaxf(sqrtf(s), 1e-6f) : 0.0f;
  }
  __syncthreads();
  // normalized bf16 rows -> vn
  float iv = sInv[kl];
  u32 ovn[8];
#pragma unroll
  for (int i = 0; i < 8; ++i) {
    float a = bf2f((u16)(vals[i] & 0xFFFF)) * iv;
    float c = bf2f((u16)(vals[i] >> 16)) * iv;
    ovn[i] = (u32)f2bf(a) | ((u32)f2bf(c) << 16);
  }
  u32* on = (u32*)(vn + ((size_t)(b * HH + h) * KPAD + key) * 64 + dc);
#pragma unroll
  for (int i = 0; i < 8; ++i) on[i] = ovn[i];
  // raw transpose -> vT
  int dl = tid >> 2, ks = (tid & 3) << 4;
  u32 ov[8];
#pragma unroll
  for (int i = 0; i < 8; ++i)
    ov[i] = (u32)tile[ks + 2 * i][dl] | ((u32)tile[ks + 2 * i + 1][dl] << 16);
  u16* o = vT + (size_t)(b * HH + h) * 64 * KPAD + (size_t)dl * KPAD + kc * 64 + ks;
#pragma unroll
  for (int i = 0; i < 8; ++i) ((u32*)o)[i] = ov[i];
}

// ---------------------------------------------------------------------------
// row0_part: grid (96,8). FUSED q0: each block recomputes its own 64-wide q0
// slice (q0[b, h*64+d] = sum_e x[0,b,e]*w_qkv[h*64+d,e]) -- 192 MAC/thread;
// the 196KB w_qkv slice is L2-shared by the 8 ck-sibling blocks (stride-96
// grid ids -> same XCD). Removes the starved 96-block q0 launch.
// Chunk ck covers keys [ck*128, +128) (ck 7 also key 1024): UNNORMALIZED
// partials num[d] = sum exp(s)*v[d], den = sum exp(s) -> part[bh][ck][65];
// vv_attn (y==0) blocks finalize row 0. exp safe in fp32 (s ~ N(0,1)).
// ---------------------------------------------------------------------------
__global__ __launch_bounds__(256) void row0_part(const float* __restrict__ x,
                                                 const float* __restrict__ wqkv,
                                                 const u16* __restrict__ kv,
                                                 float* __restrict__ part) {
  __shared__ float sq[64];
  __shared__ float sc[129];
  __shared__ float red[256];
  __shared__ float rpv[32][68];  // [key-part][dim], +4 pad breaks bank alias
  int bh = blockIdx.x, ck = blockIdx.y;
  int b = bh / HH, h = bh - b * HH;
  int tid = threadIdx.x;

  // --- fused q0 slice: 4 threads per output dim, 192 floats each ---
  {
    int part4 = tid & 3;
    const float4* x4 = (const float4*)(x + (size_t)b * DD + part4 * 192);
    const float4* w4 = (const float4*)(wqkv + (size_t)(h * 64 + (tid >> 2)) * DD + part4 * 192);
    float acc = 0.f;
#pragma unroll 4
    for (int e = 0; e < 48; ++e) {
      float4 a = x4[e], w = w4[e];
      acc += a.x * w.x + a.y * w.y + a.z * w.z + a.w * w.w;
    }
    red[tid] = acc;
  }
  if (tid == 0) sc[128] = 0.f;
  __syncthreads();
  if ((tid & 3) == 0) sq[tid >> 2] = red[tid] + red[tid + 1] + red[tid + 2] + red[tid + 3];
  __syncthreads();

  const int nk = (ck == 7) ? 129 : 128;  // chunk 7 also owns key 1024
  if (tid < nk) {
    int n = ck * 128 + tid;  // tid==128 -> n==1024
    const u32* kr = (const u32*)(kv + ((size_t)b * NSEQ + n) * 1536 + h * 64);
    float s = 0.f;
#pragma unroll
    for (int i = 0; i < 32; ++i) {
      u32 u = kr[i];
      s += bf2f((u16)(u & 0xFFFF)) * sq[2 * i] + bf2f((u16)(u >> 16)) * sq[2 * i + 1];
    }
    sc[tid] = __expf(s * 0.125f);
  }
  __syncthreads();
  // den partial
  float ds = (tid < nk) ? sc[tid] : 0.f;
  red[tid] = ds;
  __syncthreads();
  for (int st = 128; st > 0; st >>= 1) {
    if (tid < st) red[tid] += red[tid + st];
    __syncthreads();
  }
  // PV partial: thread (kp, dc) accumulates dims [dc,dc+8) over local keys kp+32j
  int kp = tid >> 3, dc = (tid & 7) << 3;
  const u16* vb = kv + (size_t)b * NSEQ * 1536 + DD + h * 64 + dc;
  float acc[8];
#pragma unroll
  for (int i = 0; i < 8; ++i) acc[i] = 0.f;
#pragma unroll
  for (int j = 0; j < 4; ++j) {
    int kl = kp + (j << 5);
    uint4 v = *(const uint4*)(vb + (size_t)(ck * 128 + kl) * 1536);
    float p = sc[kl];
    acc[0] += p * bf2f((u16)(v.x & 0xFFFF));
    acc[1] += p * bf2f((u16)(v.x >> 16));
    acc[2] += p * bf2f((u16)(v.y & 0xFFFF));
    acc[3] += p * bf2f((u16)(v.y >> 16));
    acc[4] += p * bf2f((u16)(v.z & 0xFFFF));
    acc[5] += p * bf2f((u16)(v.z >> 16));
    acc[6] += p * bf2f((u16)(v.w & 0xFFFF));
    acc[7] += p * bf2f((u16)(v.w >> 16));
  }
  if (ck == 7 && kp == 0) {  // key 1024
    uint4 v = *(const uint4*)(vb + (size_t)1024 * 1536);
    float p = sc[128];
    acc[0] += p * bf2f((u16)(v.x & 0xFFFF));
    acc[1] += p * bf2f((u16)(v.x >> 16));
    acc[2] += p * bf2f((u16)(v.y & 0xFFFF));
    acc[3] += p * bf2f((u16)(v.y >> 16));
    acc[4] += p * bf2f((u16)(v.z & 0xFFFF));
    acc[5] += p * bf2f((u16)(v.z >> 16));
    acc[6] += p * bf2f((u16)(v.w & 0xFFFF));
    acc[7] += p * bf2f((u16)(v.w >> 16));
  }
#pragma unroll
  for (int i = 0; i < 8; ++i) rpv[kp][dc + i] = acc[i];
  __syncthreads();
  float* po = part + ((size_t)bh * 8 + ck) * 65;
  if (tid < 64) {
    float s = 0.f;
#pragma unroll
    for (int p = 0; p < 32; ++p) s += rpv[p][tid];
    po[tid] = s;
  }
  if (tid == 64) po[64] = red[0];
}

// ---------------------------------------------------------------------------
// vv_attn: per (bh, 128-q-tile): S^T = Kn·Qn^T (MFMA), p = exp2(s*CEXP),
// P->LDS, out += P@V^T, den += P@ones. Grid (96,8): blocks sharing a bh have
// linear-id stride 96 = 0 mod 8 -> same XCD -> K/V stays L2-resident.
//
// v6 = v5 (structural floor: conflict-free fragment-ordered LDS, Q-in-regs,
// merged sP, one fence pair/kt) + T5 s_setprio around the MFMA clusters:
// waves here have role diversity (no barrier between QK and PV; co-resident
// blocks at different kt), the regime where setprio measured +4-7% on attn.
// ---------------------------------------------------------------------------
__global__ __launch_bounds__(256, 4) void vv_attn(const u16* __restrict__ vn,
                                                  const u16* __restrict__ vT,
                                                  u16* __restrict__ attn,
                                                  const float* __restrict__ part) {
  __shared__ u16 sK[4096];  // [kk(2)][kg(4)][lane][8]   8KB
  __shared__ u16 sV[4096];  // [kh(2)][dg(4)][lane][8]   8KB
  __shared__ u16 sP[8192];  // [w][h2][nt][mi][lr>>1][lc][lr&1][4]  16KB

  const int tid = threadIdx.x, w = tid >> 6, lane = tid & 63;
  const int lc = lane & 15, lr = lane >> 4;
  const int bh = blockIdx.x;        // 0..95
  const int m0 = blockIdx.y << 7;
  const int b = bh / HH, h = bh - b * HH;
  const char* nb = (const char*)(vn + (size_t)bh * KPAD * 64);  // 128B rows
  const char* tb = (const char*)(vT + (size_t)bh * 64 * KPAD);  // 2176B rows

  // Q fragments in registers: wave w owns q-rows [m0+w*32, +32).
  // qreg[kk][nt]: lane holds Q[1+m0+(w<<5)+(nt<<4)+lc][kk*32+lr*8 .. +8)
  short8 qreg[2][2];
#pragma unroll
  for (int kk = 0; kk < 2; ++kk)
#pragma unroll
    for (int nt = 0; nt < 2; ++nt)
      qreg[kk][nt] = *(const short8*)(nb +
          (size_t)(1 + m0 + (w << 5) + (nt << 4) + lc) * 128 + (kk << 6) + (lr << 4));

  // staging source/dest offsets; per kt: K source advances 8192B, V 128B
  const char* srcK[2];
  const char* srcV[2];
  int offKV[2];
#pragma unroll
  for (int j = 0; j < 2; ++j) {
    int lin = (w << 11) + (j << 10) + (lane << 4);
    int kk = lin >> 12, kg = (lin >> 10) & 3;
    int lr2 = (lin >> 8) & 3, lc2 = (lin >> 4) & 15;
    srcK[j] = nb + (size_t)((kg << 4) + lc2) * 128 + (kk << 6) + (lr2 << 4);
    srcV[j] = tb + (size_t)((kg << 4) + lc2) * (KPAD * 2) + (kk << 6) + (lr2 << 4);
    offKV[j] = lin;
  }

  f32x4 zero4 = {0.f, 0.f, 0.f, 0.f};
  f32x4 oacc[2][4];
  f32x4 dacc[2];
#pragma unroll
  for (int i = 0; i < 2; ++i) {
    dacc[i] = zero4;
#pragma unroll
    for (int j = 0; j < 4; ++j) oacc[i][j] = zero4;
  }
  short8 ones;
#pragma unroll
  for (int i = 0; i < 8; ++i) ones[i] = (short)0x3F80;  // bf16 1.0

  const float CEXP = 0.1803368801111204f;  // 0.125 * log2(e)

  const char* rdK = (const char*)sK + (lane << 4);
  const char* rdV = (const char*)sV + (lane << 4);
  const char* rdP = (const char*)sP + (w << 12) + (lane << 4);
  char* wrP = (char*)sP + (w << 12) + ((lr >> 1) << 8) + (lc << 4) + ((lr & 1) << 3);

#pragma unroll 1
  for (int kt = 0; kt < 17; ++kt) {
    __syncthreads();  // protect sK/sV (and order prior-kt sP reads vs writes)
#pragma unroll
    for (int j = 0; j < 2; ++j) {
      gl2lds16(srcK[j] + (size_t)kt * 8192, (char*)sK + offKV[j]);
      gl2lds16(srcV[j] + (size_t)kt * 128,  (char*)sV + offKV[j]);
    }
    __syncthreads();  // vmcnt(0) drain + publish block-wide

    // S^T = Kn_tile @ Qn^T  (C rows = 64 keys, cols = 32 queries of wave w)
    f32x4 sacc[4][2];
#pragma unroll
    for (int mt = 0; mt < 4; ++mt)
#pragma unroll
      for (int nt = 0; nt < 2; ++nt) sacc[mt][nt] = zero4;
#pragma unroll
    for (int kk = 0; kk < 2; ++kk) {
      short8 ak[4];
#pragma unroll
      for (int mt = 0; mt < 4; ++mt)
        ak[mt] = *(const short8*)(rdK + (kk << 12) + (mt << 10));
      __builtin_amdgcn_s_setprio(1);
#pragma unroll
      for (int mt = 0; mt < 4; ++mt)
#pragma unroll
        for (int nt = 0; nt < 2; ++nt)
          sacc[mt][nt] = __builtin_amdgcn_mfma_f32_16x16x32_bf16(ak[mt], qreg[kk][nt], sacc[mt][nt], 0, 0, 0);
      __builtin_amdgcn_s_setprio(0);
    }

    // p = exp2(s*CEXP) -> bf16 (+0x8000 round + perm pack) for ALL 64 keys,
    // scattered to distinct sP addresses; ONE fence pair; then all PV.
#pragma unroll
    for (int mt = 0; mt < 4; ++mt) {
#pragma unroll
      for (int nt = 0; nt < 2; ++nt) {
        f32x4 s = sacc[mt][nt];
        u32 a0 = __float_as_uint(__builtin_amdgcn_exp2f(s[0] * CEXP)) + 0x8000u;
        u32 a1 = __float_as_uint(__builtin_amdgcn_exp2f(s[1] * CEXP)) + 0x8000u;
        u32 a2 = __float_as_uint(__builtin_amdgcn_exp2f(s[2] * CEXP)) + 0x8000u;
        u32 a3 = __float_as_uint(__builtin_amdgcn_exp2f(s[3] * CEXP)) + 0x8000u;
        uint2 pv;
        pv.x = __builtin_amdgcn_perm(a1, a0, 0x07060302u);
        pv.y = __builtin_amdgcn_perm(a3, a2, 0x07060302u);
        if (kt == 16) {  // only global key 1024 (mt==0, lr==0, elem 0) valid
          pv.x = (mt == 0 && lr == 0) ? (pv.x & 0xFFFFu) : 0u;
          pv.y = 0u;
        }
        *(uint2*)(wrP + ((mt >> 1) << 11) + (nt << 10) + ((mt & 1) << 9)) = pv;
      }
    }
    __builtin_amdgcn_sched_barrier(0);
    asm volatile("" ::: "memory");  // wave-private sP: pin write->read order

#pragma unroll
    for (int h2 = 0; h2 < 2; ++h2) {
      if (!(kt == 16 && h2 == 1)) {  // keys 1056.. are all padding: skip
        short8 ap[2], bv[4];
#pragma unroll
        for (int mt = 0; mt < 2; ++mt)
          ap[mt] = *(const short8*)(rdP + (h2 << 11) + (mt << 10));
#pragma unroll
        for (int nt = 0; nt < 4; ++nt)
          bv[nt] = *(const short8*)(rdV + (h2 << 12) + (nt << 10));
        __builtin_amdgcn_s_setprio(1);
#pragma unroll
        for (int mt = 0; mt < 2; ++mt) {
#pragma unroll
          for (int nt = 0; nt < 4; ++nt)
            oacc[mt][nt] = __builtin_amdgcn_mfma_f32_16x16x32_bf16(ap[mt], bv[nt], oacc[mt][nt], 0, 0, 0);
          dacc[mt] = __builtin_amdgcn_mfma_f32_16x16x32_bf16(ap[mt], ones, dacc[mt], 0, 0, 0);
        }
        __builtin_amdgcn_s_setprio(0);
      }
    }
  }

  // epilogue: out/den -> attn rows 1+m0+q
#pragma unroll
  for (int mt = 0; mt < 2; ++mt) {
#pragma unroll
    for (int r = 0; r < 4; ++r) {
      int q = (w << 5) + (mt << 4) + (lr << 2) + r;
      int nseq = 1 + m0 + q;
      float rdn = 1.0f / dacc[mt][r];
      size_t obase = ((size_t)b * NSEQ + nseq) * DD + h * 64 + lc;
#pragma unroll
      for (int nt = 0; nt < 4; ++nt) attn[obase + (nt << 4)] = f2bf(oacc[mt][nt][r] * rdn);
    }
  }

  // finalize attention row 0 from row0_part partials (y==0 blocks only)
  if (blockIdx.y == 0 && tid < 64) {
    const float* pp = part + (size_t)bh * 8 * 65;
    float num = 0.f, den = 0.f;
#pragma unroll
    for (int c = 0; c < 8; ++c) {
      num += pp[c * 65 + tid];
      den += pp[c * 65 + 64];
    }
    attn[(size_t)b * NSEQ * DD + h * 64 + tid] = f2bf(num / den);
  }
}

// ---------------------------------------------------------------------------
// launcher
// ---------------------------------------------------------------------------
extern "C" void kernel_launch(void* const* d_in, const int* in_sizes, int n_in,
                              void* d_out, int out_size, void* d_ws, size_t ws_size,
                              hipStream_t stream) {
  const float* x      = (const float*)d_in[0];
  const float* w_qkv  = (const float*)d_in[1];
  const float* w_proj = (const float*)d_in[2];
  const float* b_proj = (const float*)d_in[3];
  float* out = (float*)d_out;
  char* ws = (char*)d_ws;

  // workspace layout (bytes). xb region is reused by vT after the qkv GEMM;
  // wkv region (dead after gemm<0>) is reused by the row-0 partials.
  u16*   xb   = (u16*)(ws + 0);            // 8320*768*2   = 12,779,520
  u16*   vT   = (u16*)(ws + 0);            // 96*64*1088*2 = 13,369,344 (reuses xb)
  u16*   wkv  = (u16*)(ws + 13369344);     // 1536*768*2   =  2,359,296
  float* r0p  = (float*)(ws + 13369344);   // 96*8*65*4    =    199,680 (reuses wkv)
  u16*   wpj  = (u16*)(ws + 15728640);     // 768*768*2    =  1,179,648
  u16*   kvb  = (u16*)(ws + 16908288);     // 8320*1536*2  = 25,559,040
  u16*   attn = (u16*)(ws + 42491904);     // 8320*768*2   = 12,779,520
  u16*   vn   = (u16*)(ws + 55271424);     // 96*1088*64*2 = 13,369,344
  // total: 68,640,768 bytes

  prep<<<7968, 256, 0, stream>>>(x, w_qkv, w_proj, xb, wkv, wpj);
  gemm_bt<0, 12><<<864, 256, 0, stream>>>(xb, wkv, kvb, nullptr, nullptr, 1536);
  row0_part<<<dim3(96, 8), 256, 0, stream>>>(x, w_qkv, kvb, r0p);
  transpose_v<<<1632, 256, 0, stream>>>(kvb, vT, vn);     // overwrites xb region
  vv_attn<<<dim3(96, 8), 256, 0, stream>>>(vn, vT, attn, r0p);
  gemm_bt<1, 6><<<432, 256, 0, stream>>>(attn, wpj, nullptr, out, b_proj, 768);
}

// Round 7
// 213.814 us; speedup vs baseline: 1.0806x; 1.0806x over previous
//
#include <hip/hip_runtime.h>

typedef unsigned short u16;
typedef unsigned int   u32;
typedef __attribute__((ext_vector_type(8))) short short8;
typedef __attribute__((ext_vector_type(4))) float f32x4;

#define AS1 __attribute__((address_space(1)))
#define AS3 __attribute__((address_space(3)))

#define NSEQ  1025
#define BB    8
#define DD    768
#define HH    12
#define MROWS 8200   // B*N valid rows
#define MPAD  8320   // padded to 65*128
#define KPAD  1088   // keys padded to 17*64

__device__ __forceinline__ void gl2lds16(const void* g, void* l) {
  __builtin_amdgcn_global_load_lds((const AS1 u32*)g, (AS3 u32*)l, 16, 0, 0);
}
__device__ __forceinline__ u16 f2bf(float f) {
  u32 u = __float_as_uint(f);
  return (u16)((u + 0x7FFFu + ((u >> 16) & 1u)) >> 16);
}
__device__ __forceinline__ float bf2f(u16 u) { return __uint_as_float(((u32)u) << 16); }

// ---------------------------------------------------------------------------
// prep: cast x -> xb bf16 [MPAD x 768] (transposed (n,b)->(b,n), pad rows = 0),
//       w_qkv rows [768,2304) -> wkv bf16 [1536 x 768],
//       w_proj -> wpj bf16 [768 x 768]
// ---------------------------------------------------------------------------
__global__ __launch_bounds__(256) void prep(const float* __restrict__ x,
                                            const float* __restrict__ wqkv,
                                            const float* __restrict__ wproj,
                                            u16* __restrict__ xb,
                                            u16* __restrict__ wkv,
                                            u16* __restrict__ wpj) {
  const int XB_G  = MPAD * 192;   // float4 groups
  const int WKV_G = 1536 * 192;
  const int WPJ_G = 768 * 192;
  int g = blockIdx.x * 256 + threadIdx.x;
  float4 v;
  u16* dst;
  size_t di;
  if (g < XB_G) {
    int m = g / 192, e4 = g - m * 192;
    if (m < MROWS) {
      int bb = m / NSEQ, ns = m - bb * NSEQ;
      v = ((const float4*)x)[(size_t)(ns * BB + bb) * 192 + e4];
    } else {
      v.x = v.y = v.z = v.w = 0.f;
    }
    dst = xb; di = (size_t)g;
  } else if (g < XB_G + WKV_G) {
    int r = g - XB_G;
    v = ((const float4*)wqkv)[(size_t)147456 + r];  // skip first 768 rows
    dst = wkv; di = (size_t)r;
  } else if (g < XB_G + WKV_G + WPJ_G) {
    int r = g - XB_G - WKV_G;
    v = ((const float4*)wproj)[r];
    dst = wpj; di = (size_t)r;
  } else {
    return;
  }
  uint2 o;
  o.x = (u32)f2bf(v.x) | ((u32)f2bf(v.y) << 16);
  o.y = (u32)f2bf(v.z) | ((u32)f2bf(v.w) << 16);
  ((uint2*)dst)[di] = o;
}

// ---------------------------------------------------------------------------
// gemm_bt: C[m,n] = sum_k A[m,k]*W[n,k]; 128x128 tile, BK=64. XCD-aware 1D
// grid. NT = n-tiles. MODE 0 (qkv GEMM): bf16 store.
// ---------------------------------------------------------------------------
template <int MODE, int NT>
__global__ __launch_bounds__(256) void gemm_bt(const u16* __restrict__ A,
                                               const u16* __restrict__ W,
                                               u16* __restrict__ Cbf,
                                               float* __restrict__ Cf,
                                               const float* __restrict__ bias,
                                               int ldc) {
  __shared__ u16 sA[128 * 64];
  __shared__ u16 sW[128 * 64];
  const int id = blockIdx.x;
  const int rx = id & 7, qx = id >> 3;
  const int kq = qx / NT;
  const int m_t = rx + (kq << 3);
  if (m_t > 64) return;
  const int n_t = qx - kq * NT;
  const int m0 = m_t << 7, n0 = n_t << 7;

  const int tid = threadIdx.x;
  const int w = tid >> 6, lane = tid & 63;
  const int wm = w & 1, wn = w >> 1;
  const int lc = lane & 15, lr = lane >> 4;

  f32x4 zero4 = {0.f, 0.f, 0.f, 0.f};
  f32x4 acc[4][4];
#pragma unroll
  for (int i = 0; i < 4; ++i)
#pragma unroll
    for (int j = 0; j < 4; ++j) acc[i][j] = zero4;

  const int r0 = tid >> 3;        // staging row 0..31 (+32 per chunk j)
  const int ko = (tid & 7) << 3;  // k-offset in elements
  const u16* gA = A + (size_t)(m0 + r0) * DD + ko;
  const u16* gW = W + (size_t)(n0 + r0) * DD + ko;
  char* lA = (char*)sA + tid * 16;
  char* lW = (char*)sW + tid * 16;

#pragma unroll 1
  for (int kt = 0; kt < 12; ++kt) {
    __syncthreads();
#pragma unroll
    for (int j = 0; j < 4; ++j) {
      gl2lds16(gA + (size_t)j * 32 * DD + kt * 64, lA + j * 4096);
      gl2lds16(gW + (size_t)j * 32 * DD + kt * 64, lW + j * 4096);
    }
    __syncthreads();
#pragma unroll
    for (int kk = 0; kk < 2; ++kk) {
      short8 af[4], wf[4];
#pragma unroll
      for (int mt = 0; mt < 4; ++mt)
        af[mt] = *(const short8*)((char*)sA + ((wm << 6) + (mt << 4) + lc) * 128 + (kk << 6) + (lr << 4));
#pragma unroll
      for (int nt = 0; nt < 4; ++nt)
        wf[nt] = *(const short8*)((char*)sW + ((wn << 6) + (nt << 4) + lc) * 128 + (kk << 6) + (lr << 4));
#pragma unroll
      for (int mt = 0; mt < 4; ++mt)
#pragma unroll
        for (int nt = 0; nt < 4; ++nt)
          acc[mt][nt] = __builtin_amdgcn_mfma_f32_16x16x32_bf16(af[mt], wf[nt], acc[mt][nt], 0, 0, 0);
    }
  }

  if (MODE == 0) {
#pragma unroll
    for (int mt = 0; mt < 4; ++mt)
#pragma unroll
      for (int r = 0; r < 4; ++r) {
        int m = m0 + (wm << 6) + (mt << 4) + (lr << 2) + r;
        if (m < MROWS) {
          size_t base = (size_t)m * ldc + n0 + (wn << 6) + lc;
#pragma unroll
          for (int nt = 0; nt < 4; ++nt) Cbf[base + (nt << 4)] = f2bf(acc[mt][nt][r]);
        }
      }
  } else {
    float b4[4];
#pragma unroll
    for (int nt = 0; nt < 4; ++nt) b4[nt] = bias[n0 + (wn << 6) + (nt << 4) + lc];
#pragma unroll
    for (int mt = 0; mt < 4; ++mt)
#pragma unroll
      for (int r = 0; r < 4; ++r) {
        int m = m0 + (wm << 6) + (mt << 4) + (lr << 2) + r;
        if (m < MROWS) {
          int bb = m / NSEQ;
          int ns = m - bb * NSEQ;
          float* o = Cf + (size_t)ns * (BB * DD) + bb * DD + n0 + (wn << 6) + lc;
#pragma unroll
          for (int nt = 0; nt < 4; ++nt) o[nt << 4] = acc[mt][nt][r] + b4[nt];
        }
      }
  }
}

// ---------------------------------------------------------------------------
// gemm_proj: proj GEMM with 128x64 tiles -> 65*12 = 780 live blocks (vs 390
// at 128x128): the old NT=6 grid was 1.5 blocks/CU -- parallelism-starved
// for a 9.8 GFLOP short-K GEMM. LDS 24KB (6 blocks/CU). Wave w owns rows
// [w*32, w*32+32) x all 64 cols; 16 MFMA/kt/wave. W-tile re-read x12 instead
// of x6 is +9MB, L2-resident. Epilogue: +bias, fp32 scatter to [N,B,D].
// ---------------------------------------------------------------------------
__global__ __launch_bounds__(256) void gemm_proj(const u16* __restrict__ A,
                                                 const u16* __restrict__ W,
                                                 float* __restrict__ Cf,
                                                 const float* __restrict__ bias) {
  __shared__ u16 sA[128 * 64];
  __shared__ u16 sW[64 * 64];
  const int id = blockIdx.x;
  const int rx = id & 7, qx = id >> 3;   // qx 0..107
  const int kq = qx / 12;                 // 0..8
  const int m_t = rx + (kq << 3);
  if (m_t > 64) return;
  const int n_t = qx - kq * 12;           // 0..11
  const int m0 = m_t << 7, n0 = n_t << 6;

  const int tid = threadIdx.x;
  const int w = tid >> 6, lane = tid & 63;
  const int lc = lane & 15, lr = lane >> 4;

  f32x4 zero4 = {0.f, 0.f, 0.f, 0.f};
  f32x4 acc[2][4];
#pragma unroll
  for (int i = 0; i < 2; ++i)
#pragma unroll
    for (int j = 0; j < 4; ++j) acc[i][j] = zero4;

  const int r0 = tid >> 3;        // staging row 0..31 (+32 per chunk j)
  const int ko = (tid & 7) << 3;  // k-offset in elements
  const u16* gA = A + (size_t)(m0 + r0) * DD + ko;
  const u16* gW = W + (size_t)(n0 + r0) * DD + ko;
  char* lA = (char*)sA + tid * 16;
  char* lW = (char*)sW + tid * 16;

#pragma unroll 1
  for (int kt = 0; kt < 12; ++kt) {
    __syncthreads();
#pragma unroll
    for (int j = 0; j < 4; ++j)
      gl2lds16(gA + (size_t)j * 32 * DD + kt * 64, lA + j * 4096);
#pragma unroll
    for (int j = 0; j < 2; ++j)
      gl2lds16(gW + (size_t)j * 32 * DD + kt * 64, lW + j * 4096);
    __syncthreads();
#pragma unroll
    for (int kk = 0; kk < 2; ++kk) {
      short8 af[2], wf[4];
#pragma unroll
      for (int mt = 0; mt < 2; ++mt)
        af[mt] = *(const short8*)((char*)sA + ((w << 5) + (mt << 4) + lc) * 128 + (kk << 6) + (lr << 4));
#pragma unroll
      for (int nt = 0; nt < 4; ++nt)
        wf[nt] = *(const short8*)((char*)sW + (((nt << 4) + lc) << 7) + (kk << 6) + (lr << 4));
#pragma unroll
      for (int mt = 0; mt < 2; ++mt)
#pragma unroll
        for (int nt = 0; nt < 4; ++nt)
          acc[mt][nt] = __builtin_amdgcn_mfma_f32_16x16x32_bf16(af[mt], wf[nt], acc[mt][nt], 0, 0, 0);
    }
  }

  float b4[4];
#pragma unroll
  for (int nt = 0; nt < 4; ++nt) b4[nt] = bias[n0 + (nt << 4) + lc];
#pragma unroll
  for (int mt = 0; mt < 2; ++mt)
#pragma unroll
    for (int r = 0; r < 4; ++r) {
      int m = m0 + (w << 5) + (mt << 4) + (lr << 2) + r;
      if (m < MROWS) {
        int bb = m / NSEQ;
        int ns = m - bb * NSEQ;
        float* o = Cf + (size_t)ns * (BB * DD) + bb * DD + n0 + lc;
#pragma unroll
        for (int nt = 0; nt < 4; ++nt) o[nt << 4] = acc[mt][nt][r] + b4[nt];
      }
    }
}

// ---------------------------------------------------------------------------
// q0: fp32 q row 0 per batch: q0[b,d'] = sum_e x[0,b,e]*w_qkv[d',e], d' in [0,768)
// ---------------------------------------------------------------------------
__global__ __launch_bounds__(256) void q0_kernel(const float* __restrict__ x,
                                                 const float* __restrict__ wq,
                                                 float* __restrict__ q0) {
  __shared__ float red[256];
  int bid = blockIdx.x;
  int b = bid / HH, c = bid - b * HH;
  int tid = threadIdx.x;
  int dp = (c << 6) + (tid >> 2), part = tid & 3;
  const float4* x4 = (const float4*)(x + (size_t)b * DD + part * 192);
  const float4* w4 = (const float4*)(wq + (size_t)dp * DD + part * 192);
  float acc = 0.f;
#pragma unroll 4
  for (int e = 0; e < 48; ++e) {
    float4 a = x4[e], w = w4[e];
    acc += a.x * w.x + a.y * w.y + a.z * w.z + a.w * w.w;
  }
  red[tid] = acc;
  __syncthreads();
  if (part == 0) q0[b * DD + dp] = red[tid] + red[tid + 1] + red[tid + 2] + red[tid + 3];
}

// ---------------------------------------------------------------------------
// transpose_v: vT[bh][d][key] raw (KPAD cols, zero-padded) AND
//              vn[bh][key][64] = v/max(||v||,eps) bf16 (zero pad rows)
// ---------------------------------------------------------------------------
__global__ __launch_bounds__(256) void transpose_v(const u16* __restrict__ kv,
                                                   u16* __restrict__ vT,
                                                   u16* __restrict__ vn) {
  __shared__ u16 tile[64][72];
  __shared__ float red[256];
  __shared__ float sInv[64];
  int bid = blockIdx.x;
  int kc = bid % 17;
  int t2 = bid / 17;
  int h = t2 % HH, b = t2 / HH;
  int tid = threadIdx.x;
  int kl = tid >> 2, dc = (tid & 3) << 4;
  int key = kc * 64 + kl;
  u32 vals[8];
  if (key < NSEQ) {
    const u32* g = (const u32*)(kv + ((size_t)b * NSEQ + key) * 1536 + DD + h * 64 + dc);
#pragma unroll
    for (int i = 0; i < 8; ++i) vals[i] = g[i];
  } else {
#pragma unroll
    for (int i = 0; i < 8; ++i) vals[i] = 0;
  }
  float part = 0.f;
#pragma unroll
  for (int i = 0; i < 8; ++i) {
    float a = bf2f((u16)(vals[i] & 0xFFFF));
    float c = bf2f((u16)(vals[i] >> 16));
    part += a * a + c * c;
    ((u32*)&tile[kl][dc])[i] = vals[i];
  }
  red[tid] = part;
  __syncthreads();
  if ((tid & 3) == 0) {
    float s = red[tid] + red[tid + 1] + red[tid + 2] + red[tid + 3];
    sInv[kl] = (key < NSEQ) ? 1.0f / fmaxf(sqrtf(s), 1e-6f) : 0.0f;
  }
  __syncthreads();
  // normalized bf16 rows -> vn
  float iv = sInv[kl];
  u32 ovn[8];
#pragma unroll
  for (int i = 0; i < 8; ++i) {
    float a = bf2f((u16)(vals[i] & 0xFFFF)) * iv;
    float c = bf2f((u16)(vals[i] >> 16)) * iv;
    ovn[i] = (u32)f2bf(a) | ((u32)f2bf(c) << 16);
  }
  u32* on = (u32*)(vn + ((size_t)(b * HH + h) * KPAD + key) * 64 + dc);
#pragma unroll
  for (int i = 0; i < 8; ++i) on[i] = ovn[i];
  // raw transpose -> vT
  int dl = tid >> 2, ks = (tid & 3) << 4;
  u32 ov[8];
#pragma unroll
  for (int i = 0; i < 8; ++i)
    ov[i] = (u32)tile[ks + 2 * i][dl] | ((u32)tile[ks + 2 * i + 1][dl] << 16);
  u16* o = vT + (size_t)(b * HH + h) * 64 * KPAD + (size_t)dl * KPAD + kc * 64 + ks;
#pragma unroll
  for (int i = 0; i < 8; ++i) ((u32*)o)[i] = ov[i];
}

// ---------------------------------------------------------------------------
// row0_part: grid (96,8). Chunk ck covers keys [ck*128, ck*128+128) (chunk 7
// also key 1024). Computes UNNORMALIZED partials: num[d] = sum exp(s)*v[d],
// den = sum exp(s). No max-subtraction: s = q0.k*0.125 ~ N(0,1), exp safe in
// fp32. Partials -> part[bh][ck][65]; vv_attn (y==0) blocks finalize row 0.
// ---------------------------------------------------------------------------
__global__ __launch_bounds__(256) void row0_part(const float* __restrict__ q0,
                                                 const u16* __restrict__ kv,
                                                 float* __restrict__ part) {
  __shared__ float sq[64];
  __shared__ float sc[129];
  __shared__ float red[256];
  __shared__ float rpv[32][68];  // [key-part][dim], +4 pad breaks bank alias
  int bh = blockIdx.x, ck = blockIdx.y;
  int b = bh / HH, h = bh - b * HH;
  int tid = threadIdx.x;
  if (tid < 64) sq[tid] = q0[b * DD + h * 64 + tid];
  if (tid == 64) sc[128] = 0.f;
  __syncthreads();
  const int nk = (ck == 7) ? 129 : 128;  // chunk 7 also owns key 1024
  if (tid < nk) {
    int n = ck * 128 + tid;  // tid==128 -> n==1024
    const u32* kr = (const u32*)(kv + ((size_t)b * NSEQ + n) * 1536 + h * 64);
    float s = 0.f;
#pragma unroll
    for (int i = 0; i < 32; ++i) {
      u32 u = kr[i];
      s += bf2f((u16)(u & 0xFFFF)) * sq[2 * i] + bf2f((u16)(u >> 16)) * sq[2 * i + 1];
    }
    sc[tid] = __expf(s * 0.125f);
  }
  __syncthreads();
  // den partial
  float ds = (tid < nk) ? sc[tid] : 0.f;
  red[tid] = ds;
  __syncthreads();
  for (int st = 128; st > 0; st >>= 1) {
    if (tid < st) red[tid] += red[tid + st];
    __syncthreads();
  }
  // PV partial: thread (kp, dc) accumulates dims [dc,dc+8) over local keys kp+32j
  int kp = tid >> 3, dc = (tid & 7) << 3;
  const u16* vb = kv + (size_t)b * NSEQ * 1536 + DD + h * 64 + dc;
  float acc[8];
#pragma unroll
  for (int i = 0; i < 8; ++i) acc[i] = 0.f;
#pragma unroll
  for (int j = 0; j < 4; ++j) {
    int kl = kp + (j << 5);
    uint4 v = *(const uint4*)(vb + (size_t)(ck * 128 + kl) * 1536);
    float p = sc[kl];
    acc[0] += p * bf2f((u16)(v.x & 0xFFFF));
    acc[1] += p * bf2f((u16)(v.x >> 16));
    acc[2] += p * bf2f((u16)(v.y & 0xFFFF));
    acc[3] += p * bf2f((u16)(v.y >> 16));
    acc[4] += p * bf2f((u16)(v.z & 0xFFFF));
    acc[5] += p * bf2f((u16)(v.z >> 16));
    acc[6] += p * bf2f((u16)(v.w & 0xFFFF));
    acc[7] += p * bf2f((u16)(v.w >> 16));
  }
  if (ck == 7 && kp == 0) {  // key 1024
    uint4 v = *(const uint4*)(vb + (size_t)1024 * 1536);
    float p = sc[128];
    acc[0] += p * bf2f((u16)(v.x & 0xFFFF));
    acc[1] += p * bf2f((u16)(v.x >> 16));
    acc[2] += p * bf2f((u16)(v.y & 0xFFFF));
    acc[3] += p * bf2f((u16)(v.y >> 16));
    acc[4] += p * bf2f((u16)(v.z & 0xFFFF));
    acc[5] += p * bf2f((u16)(v.z >> 16));
    acc[6] += p * bf2f((u16)(v.w & 0xFFFF));
    acc[7] += p * bf2f((u16)(v.w >> 16));
  }
#pragma unroll
  for (int i = 0; i < 8; ++i) rpv[kp][dc + i] = acc[i];
  __syncthreads();
  float* po = part + ((size_t)bh * 8 + ck) * 65;
  if (tid < 64) {
    float s = 0.f;
#pragma unroll
    for (int p = 0; p < 32; ++p) s += rpv[p][tid];
    po[tid] = s;
  }
  if (tid == 64) po[64] = red[0];
}

// ---------------------------------------------------------------------------
// vv_attn: per (bh, 128-q-tile): S^T = Kn·Qn^T (MFMA), p = exp2(s*CEXP),
// P->LDS, out += P@V^T, den += P@ones. Grid (96,8): blocks sharing a bh have
// linear-id stride 96 = 0 mod 8 -> same XCD -> K/V stays L2-resident.
//
// r5 structure (measured floor for this schedule): conflict-free fragment-
// ordered LDS, Q-in-regs, merged sP (one fence pair/kt), single-buffer K/V,
// 2 barriers/kt. Structural experiments measured: conflict-fix -5us; dbuf,
// occupancy-2x, fence-merge, setprio all null.
// ---------------------------------------------------------------------------
__global__ __launch_bounds__(256, 4) void vv_attn(const u16* __restrict__ vn,
                                                  const u16* __restrict__ vT,
                                                  u16* __restrict__ attn,
                                                  const float* __restrict__ part) {
  __shared__ u16 sK[4096];  // [kk(2)][kg(4)][lane][8]   8KB
  __shared__ u16 sV[4096];  // [kh(2)][dg(4)][lane][8]   8KB
  __shared__ u16 sP[8192];  // [w][h2][nt][mi][lr>>1][lc][lr&1][4]  16KB

  const int tid = threadIdx.x, w = tid >> 6, lane = tid & 63;
  const int lc = lane & 15, lr = lane >> 4;
  const int bh = blockIdx.x;        // 0..95
  const int m0 = blockIdx.y << 7;
  const int b = bh / HH, h = bh - b * HH;
  const char* nb = (const char*)(vn + (size_t)bh * KPAD * 64);  // 128B rows
  const char* tb = (const char*)(vT + (size_t)bh * 64 * KPAD);  // 2176B rows

  // Q fragments in registers: wave w owns q-rows [m0+w*32, +32).
  // qreg[kk][nt]: lane holds Q[1+m0+(w<<5)+(nt<<4)+lc][kk*32+lr*8 .. +8)
  short8 qreg[2][2];
#pragma unroll
  for (int kk = 0; kk < 2; ++kk)
#pragma unroll
    for (int nt = 0; nt < 2; ++nt)
      qreg[kk][nt] = *(const short8*)(nb +
          (size_t)(1 + m0 + (w << 5) + (nt << 4) + lc) * 128 + (kk << 6) + (lr << 4));

  // staging source/dest offsets; per kt: K source advances 8192B, V 128B
  const char* srcK[2];
  const char* srcV[2];
  int offKV[2];
#pragma unroll
  for (int j = 0; j < 2; ++j) {
    int lin = (w << 11) + (j << 10) + (lane << 4);
    int kk = lin >> 12, kg = (lin >> 10) & 3;
    int lr2 = (lin >> 8) & 3, lc2 = (lin >> 4) & 15;
    srcK[j] = nb + (size_t)((kg << 4) + lc2) * 128 + (kk << 6) + (lr2 << 4);
    srcV[j] = tb + (size_t)((kg << 4) + lc2) * (KPAD * 2) + (kk << 6) + (lr2 << 4);
    offKV[j] = lin;
  }

  f32x4 zero4 = {0.f, 0.f, 0.f, 0.f};
  f32x4 oacc[2][4];
  f32x4 dacc[2];
#pragma unroll
  for (int i = 0; i < 2; ++i) {
    dacc[i] = zero4;
#pragma unroll
    for (int j = 0; j < 4; ++j) oacc[i][j] = zero4;
  }
  short8 ones;
#pragma unroll
  for (int i = 0; i < 8; ++i) ones[i] = (short)0x3F80;  // bf16 1.0

  const float CEXP = 0.1803368801111204f;  // 0.125 * log2(e)

  const char* rdK = (const char*)sK + (lane << 4);
  const char* rdV = (const char*)sV + (lane << 4);
  const char* rdP = (const char*)sP + (w << 12) + (lane << 4);
  char* wrP = (char*)sP + (w << 12) + ((lr >> 1) << 8) + (lc << 4) + ((lr & 1) << 3);

#pragma unroll 1
  for (int kt = 0; kt < 17; ++kt) {
    __syncthreads();  // protect sK/sV (and order prior-kt sP reads vs writes)
#pragma unroll
    for (int j = 0; j < 2; ++j) {
      gl2lds16(srcK[j] + (size_t)kt * 8192, (char*)sK + offKV[j]);
      gl2lds16(srcV[j] + (size_t)kt * 128,  (char*)sV + offKV[j]);
    }
    __syncthreads();  // vmcnt(0) drain + publish block-wide

    // S^T = Kn_tile @ Qn^T  (C rows = 64 keys, cols = 32 queries of wave w)
    f32x4 sacc[4][2];
#pragma unroll
    for (int mt = 0; mt < 4; ++mt)
#pragma unroll
      for (int nt = 0; nt < 2; ++nt) sacc[mt][nt] = zero4;
#pragma unroll
    for (int kk = 0; kk < 2; ++kk) {
      short8 ak[4];
#pragma unroll
      for (int mt = 0; mt < 4; ++mt)
        ak[mt] = *(const short8*)(rdK + (kk << 12) + (mt << 10));
#pragma unroll
      for (int mt = 0; mt < 4; ++mt)
#pragma unroll
        for (int nt = 0; nt < 2; ++nt)
          sacc[mt][nt] = __builtin_amdgcn_mfma_f32_16x16x32_bf16(ak[mt], qreg[kk][nt], sacc[mt][nt], 0, 0, 0);
    }

    // p = exp2(s*CEXP) -> bf16 (+0x8000 round + perm pack) for ALL 64 keys,
    // scattered to distinct sP addresses; ONE fence pair; then all PV.
#pragma unroll
    for (int mt = 0; mt < 4; ++mt) {
#pragma unroll
      for (int nt = 0; nt < 2; ++nt) {
        f32x4 s = sacc[mt][nt];
        u32 a0 = __float_as_uint(__builtin_amdgcn_exp2f(s[0] * CEXP)) + 0x8000u;
        u32 a1 = __float_as_uint(__builtin_amdgcn_exp2f(s[1] * CEXP)) + 0x8000u;
        u32 a2 = __float_as_uint(__builtin_amdgcn_exp2f(s[2] * CEXP)) + 0x8000u;
        u32 a3 = __float_as_uint(__builtin_amdgcn_exp2f(s[3] * CEXP)) + 0x8000u;
        uint2 pv;
        pv.x = __builtin_amdgcn_perm(a1, a0, 0x07060302u);
        pv.y = __builtin_amdgcn_perm(a3, a2, 0x07060302u);
        if (kt == 16) {  // only global key 1024 (mt==0, lr==0, elem 0) valid
          pv.x = (mt == 0 && lr == 0) ? (pv.x & 0xFFFFu) : 0u;
          pv.y = 0u;
        }
        *(uint2*)(wrP + ((mt >> 1) << 11) + (nt << 10) + ((mt & 1) << 9)) = pv;
      }
    }
    __builtin_amdgcn_sched_barrier(0);
    asm volatile("" ::: "memory");  // wave-private sP: pin write->read order

#pragma unroll
    for (int h2 = 0; h2 < 2; ++h2) {
      if (!(kt == 16 && h2 == 1)) {  // keys 1056.. are all padding: skip
        short8 ap[2], bv[4];
#pragma unroll
        for (int mt = 0; mt < 2; ++mt)
          ap[mt] = *(const short8*)(rdP + (h2 << 11) + (mt << 10));
#pragma unroll
        for (int nt = 0; nt < 4; ++nt)
          bv[nt] = *(const short8*)(rdV + (h2 << 12) + (nt << 10));
#pragma unroll
        for (int mt = 0; mt < 2; ++mt) {
#pragma unroll
          for (int nt = 0; nt < 4; ++nt)
            oacc[mt][nt] = __builtin_amdgcn_mfma_f32_16x16x32_bf16(ap[mt], bv[nt], oacc[mt][nt], 0, 0, 0);
          dacc[mt] = __builtin_amdgcn_mfma_f32_16x16x32_bf16(ap[mt], ones, dacc[mt], 0, 0, 0);
        }
      }
    }
  }

  // epilogue: out/den -> attn rows 1+m0+q
#pragma unroll
  for (int mt = 0; mt < 2; ++mt) {
#pragma unroll
    for (int r = 0; r < 4; ++r) {
      int q = (w << 5) + (mt << 4) + (lr << 2) + r;
      int nseq = 1 + m0 + q;
      float rdn = 1.0f / dacc[mt][r];
      size_t obase = ((size_t)b * NSEQ + nseq) * DD + h * 64 + lc;
#pragma unroll
      for (int nt = 0; nt < 4; ++nt) attn[obase + (nt << 4)] = f2bf(oacc[mt][nt][r] * rdn);
    }
  }

  // finalize attention row 0 from row0_part partials (y==0 blocks only)
  if (blockIdx.y == 0 && tid < 64) {
    const float* pp = part + (size_t)bh * 8 * 65;
    float num = 0.f, den = 0.f;
#pragma unroll
    for (int c = 0; c < 8; ++c) {
      num += pp[c * 65 + tid];
      den += pp[c * 65 + 64];
    }
    attn[(size_t)b * NSEQ * DD + h * 64 + tid] = f2bf(num / den);
  }
}

// ---------------------------------------------------------------------------
// launcher
// ---------------------------------------------------------------------------
extern "C" void kernel_launch(void* const* d_in, const int* in_sizes, int n_in,
                              void* d_out, int out_size, void* d_ws, size_t ws_size,
                              hipStream_t stream) {
  const float* x      = (const float*)d_in[0];
  const float* w_qkv  = (const float*)d_in[1];
  const float* w_proj = (const float*)d_in[2];
  const float* b_proj = (const float*)d_in[3];
  float* out = (float*)d_out;
  char* ws = (char*)d_ws;

  // workspace layout (bytes). xb region is reused by vT after the qkv GEMM;
  // wkv region (dead after gemm<0>) is reused by the row-0 partials.
  u16*   xb   = (u16*)(ws + 0);            // 8320*768*2   = 12,779,520
  u16*   vT   = (u16*)(ws + 0);            // 96*64*1088*2 = 13,369,344 (reuses xb)
  u16*   wkv  = (u16*)(ws + 13369344);     // 1536*768*2   =  2,359,296
  float* r0p  = (float*)(ws + 13369344);   // 96*8*65*4    =    199,680 (reuses wkv)
  u16*   wpj  = (u16*)(ws + 15728640);     // 768*768*2    =  1,179,648
  u16*   kvb  = (u16*)(ws + 16908288);     // 8320*1536*2  = 25,559,040
  float* q0   = (float*)(ws + 42467328);   // 8*768*4      =     24,576
  u16*   attn = (u16*)(ws + 42491904);     // 8320*768*2   = 12,779,520
  u16*   vn   = (u16*)(ws + 55271424);     // 96*1088*64*2 = 13,369,344
  // total: 68,640,768 bytes

  prep<<<7968, 256, 0, stream>>>(x, w_qkv, w_proj, xb, wkv, wpj);
  gemm_bt<0, 12><<<864, 256, 0, stream>>>(xb, wkv, kvb, nullptr, nullptr, 1536);
  q0_kernel<<<96, 256, 0, stream>>>(x, w_qkv, q0);
  transpose_v<<<1632, 256, 0, stream>>>(kvb, vT, vn);     // overwrites xb region
  row0_part<<<dim3(96, 8), 256, 0, stream>>>(q0, kvb, r0p);
  vv_attn<<<dim3(96, 8), 256, 0, stream>>>(vn, vT, attn, r0p);
  gemm_proj<<<864, 256, 0, stream>>>(attn, wpj, out, b_proj);
}